// Round 3
// baseline (491.549 us; speedup 1.0000x reference)
//
#include <hip/hip_runtime.h>
#include <stdint.h>

typedef __bf16 bf16x8 __attribute__((ext_vector_type(8)));
typedef float f32x4 __attribute__((ext_vector_type(4)));

__device__ __forceinline__ float bf2f(unsigned short s) {
    union { unsigned u; float f; } x; x.u = ((unsigned)s) << 16; return x.f;
}
__device__ __forceinline__ unsigned short f2bf(float f) {
    union { float f; unsigned u; } x; x.f = f;
    unsigned r = x.u + 0x7fffu + ((x.u >> 16) & 1u);
    return (unsigned short)(r >> 16);
}

// ---------- CSR build ----------
__global__ void k_degree(const int* __restrict__ dst, int E, int* __restrict__ deg) {
    int i = blockIdx.x * blockDim.x + threadIdx.x;
    if (i < E) atomicAdd(&deg[dst[i]], 1);
}

__global__ void k_dinv(const int* __restrict__ deg, float* __restrict__ dinv, int N) {
    int i = blockIdx.x * blockDim.x + threadIdx.x;
    if (i < N) dinv[i] = rsqrtf((float)deg[i] + 1.0f);  // +1 = self loop
}

// ---------- hierarchical scan: deg[N] -> row_ptr[N+1] (exclusive) ----------
__global__ __launch_bounds__(256) void k_scan_part(const int* __restrict__ deg,
                                                   int* __restrict__ part, int N) {
    __shared__ int wsum[4];
    int t = threadIdx.x;
    int lane = t & 63, wv = t >> 6;
    int base = blockIdx.x * 1024 + t * 4;
    int s = 0;
#pragma unroll
    for (int j = 0; j < 4; ++j) {
        int i = base + j;
        if (i < N) s += deg[i];
    }
    for (int off = 1; off < 64; off <<= 1) s += __shfl_xor(s, off, 64);
    if (lane == 0) wsum[wv] = s;
    __syncthreads();
    if (t == 0) part[blockIdx.x] = wsum[0] + wsum[1] + wsum[2] + wsum[3];
}

__global__ void k_scan_mid(int* __restrict__ part, int nb) {
    __shared__ int buf[256];
    int t = threadIdx.x;
    buf[t] = (t < nb) ? part[t] : 0;
    __syncthreads();
    for (int off = 1; off < 256; off <<= 1) {
        int v = buf[t];
        int u = (t >= off) ? buf[t - off] : 0;
        __syncthreads();
        buf[t] = v + u;
        __syncthreads();
    }
    if (t < nb) part[t] = (t == 0) ? 0 : buf[t - 1];
}

__global__ __launch_bounds__(256) void k_scan_final(const int* __restrict__ deg,
                                                    const int* __restrict__ part,
                                                    int* __restrict__ row_ptr, int N) {
    __shared__ int wsum[4];
    int t = threadIdx.x;
    int lane = t & 63, wv = t >> 6;
    int base = blockIdx.x * 1024 + t * 4;
    int v[4];
    int s = 0;
#pragma unroll
    for (int j = 0; j < 4; ++j) {
        int i = base + j;
        v[j] = (i < N) ? deg[i] : 0;
        s += v[j];
    }
    int inc = s;
    for (int off = 1; off < 64; off <<= 1) {
        int u = __shfl_up(inc, off, 64);
        if (lane >= off) inc += u;
    }
    if (lane == 63) wsum[wv] = inc;
    __syncthreads();
    int excl = part[blockIdx.x] + inc - s;
    for (int w = 0; w < wv; ++w) excl += wsum[w];
#pragma unroll
    for (int j = 0; j < 4; ++j) {
        int i = base + j;
        if (i < N) {
            row_ptr[i] = excl;
            excl += v[j];
            if (i == N - 1) row_ptr[N] = excl;
        }
    }
}

// fill[] starts as a copy of row_ptr[0..N); atomically bump to place each edge.
__global__ void k_scatter(const int* __restrict__ src, const int* __restrict__ dst, int E,
                          int* __restrict__ fill, int* __restrict__ ssrc) {
    int e = blockIdx.x * blockDim.x + threadIdx.x;
    if (e >= E) return;
    int s = src[e], d = dst[e];
    int pos = atomicAdd(&fill[d], 1);
    ssrc[pos] = s;
}

// ---------- conversions ----------
__global__ void k_cvt_x(const float4* __restrict__ x, ushort4* __restrict__ out, int n4) {
    int i = blockIdx.x * blockDim.x + threadIdx.x;
    if (i < n4) {
        float4 v = x[i];
        ushort4 o;
        o.x = f2bf(v.x); o.y = f2bf(v.y); o.z = f2bf(v.z); o.w = f2bf(v.w);
        out[i] = o;
    }
}

// W [K=128][realCols] f32 row-major -> fragment layout bf16:
// Wf[((kk*NT + n)*64 + lane)*8 + j] = W[kk*32 + (lane>>4)*8 + j][n*16 + (lane&15)]
__global__ void k_wfrag(const float* __restrict__ W, unsigned short* __restrict__ Wf,
                        int Ncol, int realCols) {
    int NT = Ncol >> 4;
    int total = 4 * NT * 64 * 8;
    int idx = blockIdx.x * blockDim.x + threadIdx.x;
    if (idx >= total) return;
    int j = idx & 7;
    int l = (idx >> 3) & 63;
    int t = idx >> 9;          // kk*NT + n
    int n = t % NT;
    int kk = t / NT;
    int k = kk * 32 + ((l >> 4) << 3) + j;
    int c = (n << 4) + (l & 15);
    float v = (c < realCols) ? W[k * realCols + c] : 0.0f;
    Wf[idx] = f2bf(v);
}

// ---------- GEMM: H'[Npad][NT*16] = dinv[row] * (A[Npad][128] @ W) ----------
template<int NT>
__global__ __launch_bounds__(256) void k_gemm(const unsigned short* __restrict__ A,
                                              const unsigned short* __restrict__ Wf,
                                              const float* __restrict__ dinv,
                                              unsigned short* __restrict__ Hout) {
    int lane = threadIdx.x & 63;
    int wv = threadIdx.x >> 6;
    int rb = blockIdx.x * 4 + wv;
    size_t row0 = (size_t)rb * 16;
    const unsigned short* arow = A + (row0 + (lane & 15)) * 128 + ((lane >> 4) << 3);
    f32x4 acc[NT];
#pragma unroll
    for (int n = 0; n < NT; ++n) acc[n] = (f32x4){0.f, 0.f, 0.f, 0.f};
#pragma unroll
    for (int kk = 0; kk < 4; ++kk) {
        bf16x8 a = *(const bf16x8*)(arow + kk * 32);
#pragma unroll
        for (int n = 0; n < NT; ++n) {
            bf16x8 b = *(const bf16x8*)(Wf + (((kk * NT + n) * 64 + lane) << 3));
            acc[n] = __builtin_amdgcn_mfma_f32_16x16x32_bf16(a, b, acc[n], 0, 0, 0);
        }
    }
    const int NCOL = NT * 16;
    size_t crow = row0 + ((lane >> 4) << 2);
    int ccol = lane & 15;
    float dv[4];
#pragma unroll
    for (int q = 0; q < 4; ++q) dv[q] = dinv[crow + q];
#pragma unroll
    for (int n = 0; n < NT; ++n) {
#pragma unroll
        for (int q = 0; q < 4; ++q) {
            Hout[(crow + q) * NCOL + n * 16 + ccol] = f2bf(acc[n][q] * dv[q]);
        }
    }
}

// ---------- aggregation (128 ch): Out[i] = relu(dinv[i]*(sum H'[src] + H'[i]) + b) ----------
__global__ __launch_bounds__(256) void k_agg(const unsigned short* __restrict__ H,
                                             const int* __restrict__ row_ptr,
                                             const int* __restrict__ ssrc,
                                             const float* __restrict__ dinv,
                                             const float* __restrict__ bias,
                                             unsigned short* __restrict__ Out, int N) {
    int lane = threadIdx.x & 63;
    int i = blockIdx.x * 4 + (threadIdx.x >> 6);
    if (i >= N) return;
    float dv = dinv[i];
    unsigned v = *(const unsigned*)(H + ((size_t)i << 7) + (lane << 1));
    float acc0 = bf2f((unsigned short)(v & 0xffff));
    float acc1 = bf2f((unsigned short)(v >> 16));
    int e = row_ptr[i], e1 = row_ptr[i + 1];
#pragma unroll 4
    for (; e < e1; ++e) {
        int s = ssrc[e];
        unsigned hv = *(const unsigned*)(H + ((size_t)s << 7) + (lane << 1));
        acc0 += bf2f((unsigned short)(hv & 0xffff));
        acc1 += bf2f((unsigned short)(hv >> 16));
    }
    acc0 = fmaxf(acc0 * dv + bias[lane * 2], 0.f);
    acc1 = fmaxf(acc1 * dv + bias[lane * 2 + 1], 0.f);
    unsigned o = (unsigned)f2bf(acc0) | ((unsigned)f2bf(acc1) << 16);
    *(unsigned*)(Out + ((size_t)i << 7) + (lane << 1)) = o;
}

// ---------- final aggregation (64-padded ch, Cout real) + bias + log_softmax ----------
__global__ __launch_bounds__(256) void k_agg3(const unsigned short* __restrict__ H,
                                              const int* __restrict__ row_ptr,
                                              const int* __restrict__ ssrc,
                                              const float* __restrict__ dinv,
                                              const float* __restrict__ b3,
                                              float* __restrict__ Out, int N, int Cout) {
    int lane = threadIdx.x & 63;
    int i = blockIdx.x * 4 + (threadIdx.x >> 6);
    if (i >= N) return;
    float dv = dinv[i];
    float acc = bf2f(H[((size_t)i << 6) + lane]);
    int e = row_ptr[i], e1 = row_ptr[i + 1];
#pragma unroll 4
    for (; e < e1; ++e) {
        int s = ssrc[e];
        acc += bf2f(H[((size_t)s << 6) + lane]);
    }
    float z = (lane < Cout) ? acc * dv + b3[lane] : -1e30f;
    float m = z;
    for (int off = 32; off; off >>= 1) m = fmaxf(m, __shfl_xor(m, off, 64));
    float p = (lane < Cout) ? expf(z - m) : 0.f;
    float ssum = p;
    for (int off = 32; off; off >>= 1) ssum += __shfl_xor(ssum, off, 64);
    if (lane < Cout) Out[(size_t)i * Cout + lane] = z - m - logf(ssum);
}

extern "C" void kernel_launch(void* const* d_in, const int* in_sizes, int n_in,
                              void* d_out, int out_size, void* d_ws, size_t ws_size,
                              hipStream_t stream) {
    const float* x  = (const float*)d_in[0];
    const int*   ei = (const int*)d_in[1];
    const float* W1 = (const float*)d_in[2];
    const float* b1 = (const float*)d_in[3];
    const float* W2 = (const float*)d_in[4];
    const float* b2 = (const float*)d_in[5];
    const float* W3 = (const float*)d_in[6];
    const float* b3 = (const float*)d_in[7];

    const int N = in_sizes[0] / 128;
    const int E = in_sizes[1] / 2;
    const int Cout = in_sizes[7];       // 47
    const int Npad = (N + 63) & ~63;
    const int* srcp = ei;
    const int* dstp = ei + E;

    // ---- workspace partition (256B aligned) ----
    char* p = (char*)d_ws;
    auto alloc = [&](size_t bytes) -> void* {
        void* r = (void*)p;
        p += (bytes + 255) & ~(size_t)255;
        return r;
    };
    int*   deg      = (int*)alloc((size_t)Npad * 4);
    float* dinv     = (float*)alloc((size_t)Npad * 4);
    int*   row_ptr  = (int*)alloc((size_t)(N + 1) * 4);
    int*   fill     = (int*)alloc((size_t)N * 4);
    int*   part     = (int*)alloc(1024 * 4);
    int*   ssrc     = (int*)alloc((size_t)E * 4);
    unsigned short* xb  = (unsigned short*)alloc((size_t)Npad * 128 * 2);
    unsigned short* hb  = (unsigned short*)alloc((size_t)Npad * 128 * 2);
    unsigned short* ab  = (unsigned short*)alloc((size_t)Npad * 128 * 2);
    unsigned short* wf1 = (unsigned short*)alloc(128 * 128 * 2);
    unsigned short* wf2 = (unsigned short*)alloc(128 * 128 * 2);
    unsigned short* wf3 = (unsigned short*)alloc(128 * 64 * 2);

    hipMemsetAsync(deg, 0, (size_t)Npad * 4, stream);

    // CSR build
    const int nb = (N + 1023) / 1024;   // 98 blocks for N=100k (must be <= 256)
    k_degree<<<(E + 255) / 256, 256, 0, stream>>>(dstp, E, deg);
    k_dinv<<<(Npad + 255) / 256, 256, 0, stream>>>(deg, dinv, Npad);
    k_scan_part<<<nb, 256, 0, stream>>>(deg, part, N);
    k_scan_mid<<<1, 256, 0, stream>>>(part, nb);
    k_scan_final<<<nb, 256, 0, stream>>>(deg, part, row_ptr, N);
    hipMemcpyAsync(fill, row_ptr, (size_t)N * 4, hipMemcpyDeviceToDevice, stream);
    k_scatter<<<(E + 255) / 256, 256, 0, stream>>>(srcp, dstp, E, fill, ssrc);

    // conversions
    k_cvt_x<<<(N * 128 / 4 + 255) / 256, 256, 0, stream>>>((const float4*)x, (ushort4*)xb,
                                                           N * 128 / 4);
    k_wfrag<<<(16384 + 255) / 256, 256, 0, stream>>>(W1, wf1, 128, 128);
    k_wfrag<<<(16384 + 255) / 256, 256, 0, stream>>>(W2, wf2, 128, 128);
    k_wfrag<<<(8192 + 255) / 256, 256, 0, stream>>>(W3, wf3, 64, Cout);

    const int gemmGrid = Npad / 64;
    const int aggGrid = (N + 3) / 4;

    // layer 1
    k_gemm<8><<<gemmGrid, 256, 0, stream>>>(xb, wf1, dinv, hb);
    k_agg<<<aggGrid, 256, 0, stream>>>(hb, row_ptr, ssrc, dinv, b1, ab, N);
    // layer 2
    k_gemm<8><<<gemmGrid, 256, 0, stream>>>(ab, wf2, dinv, hb);
    k_agg<<<aggGrid, 256, 0, stream>>>(hb, row_ptr, ssrc, dinv, b2, ab, N);
    // layer 3 (output padded to 64 cols) + log_softmax
    k_gemm<4><<<gemmGrid, 256, 0, stream>>>(ab, wf3, dinv, hb);
    k_agg3<<<aggGrid, 256, 0, stream>>>(hb, row_ptr, ssrc, dinv, b3,
                                        (float*)d_out, N, Cout);
}

// Round 4
// 331.512 us; speedup vs baseline: 1.4827x; 1.4827x over previous
//
#include <hip/hip_runtime.h>
#include <stdint.h>

typedef __bf16 bf16x8 __attribute__((ext_vector_type(8)));
typedef float f32x4 __attribute__((ext_vector_type(4)));

#define CHB 8192  // edges per partition block

__device__ __forceinline__ float bf2f(unsigned short s) {
    union { unsigned u; float f; } x; x.u = ((unsigned)s) << 16; return x.f;
}
__device__ __forceinline__ unsigned short f2bf(float f) {
    union { float f; unsigned u; } x; x.f = f;
    unsigned r = x.u + 0x7fffu + ((x.u >> 16) & 1u);
    return (unsigned short)(r >> 16);
}

// ---------- pass A: per-(bucket,block) histogram. bucket = dst>>9 ----------
__global__ __launch_bounds__(256) void k_hist(const int* __restrict__ dst, int E, int nPB,
                                              int* __restrict__ bhist, int NB) {
    __shared__ int h[256];
    int t = threadIdx.x;
    h[t] = 0;
    __syncthreads();
    int blk = blockIdx.x;
    int hi = min((blk + 1) * CHB, E);
    for (int e = blk * CHB + t; e < hi; e += 256) atomicAdd(&h[dst[e] >> 9], 1);
    __syncthreads();
    if (t < NB) bhist[t * nPB + blk] = h[t];
}

// ---------- hierarchical scan (generic): in[M] -> out[M+1] exclusive ----------
__global__ __launch_bounds__(256) void k_scan_part(const int* __restrict__ deg,
                                                   int* __restrict__ part, int N) {
    __shared__ int wsum[4];
    int t = threadIdx.x;
    int lane = t & 63, wv = t >> 6;
    int base = blockIdx.x * 1024 + t * 4;
    int s = 0;
#pragma unroll
    for (int j = 0; j < 4; ++j) {
        int i = base + j;
        if (i < N) s += deg[i];
    }
    for (int off = 1; off < 64; off <<= 1) s += __shfl_xor(s, off, 64);
    if (lane == 0) wsum[wv] = s;
    __syncthreads();
    if (t == 0) part[blockIdx.x] = wsum[0] + wsum[1] + wsum[2] + wsum[3];
}

__global__ void k_scan_mid(int* __restrict__ part, int nb) {
    __shared__ int buf[256];
    int t = threadIdx.x;
    buf[t] = (t < nb) ? part[t] : 0;
    __syncthreads();
    for (int off = 1; off < 256; off <<= 1) {
        int v = buf[t];
        int u = (t >= off) ? buf[t - off] : 0;
        __syncthreads();
        buf[t] = v + u;
        __syncthreads();
    }
    if (t < nb) part[t] = (t == 0) ? 0 : buf[t - 1];
}

__global__ __launch_bounds__(256) void k_scan_final(const int* __restrict__ deg,
                                                    const int* __restrict__ part,
                                                    int* __restrict__ out, int N) {
    __shared__ int wsum[4];
    int t = threadIdx.x;
    int lane = t & 63, wv = t >> 6;
    int base = blockIdx.x * 1024 + t * 4;
    int v[4];
    int s = 0;
#pragma unroll
    for (int j = 0; j < 4; ++j) {
        int i = base + j;
        v[j] = (i < N) ? deg[i] : 0;
        s += v[j];
    }
    int inc = s;
    for (int off = 1; off < 64; off <<= 1) {
        int u = __shfl_up(inc, off, 64);
        if (lane >= off) inc += u;
    }
    if (lane == 63) wsum[wv] = inc;
    __syncthreads();
    int excl = part[blockIdx.x] + inc - s;
    for (int w = 0; w < wv; ++w) excl += wsum[w];
#pragma unroll
    for (int j = 0; j < 4; ++j) {
        int i = base + j;
        if (i < N) {
            out[i] = excl;
            excl += v[j];
            if (i == N - 1) out[N] = excl;
        }
    }
}

// ---------- pass B: partition edges into bucket-contiguous regions ----------
__global__ __launch_bounds__(256) void k_partition(const int* __restrict__ src,
                                                   const int* __restrict__ dst, int E,
                                                   int nPB, const int* __restrict__ bscan,
                                                   unsigned* __restrict__ part_edges, int NB) {
    __shared__ int cur[256];
    int t = threadIdx.x;
    int blk = blockIdx.x;
    if (t < NB) cur[t] = bscan[t * nPB + blk];
    __syncthreads();
    int hi = min((blk + 1) * CHB, E);
    for (int e = blk * CHB + t; e < hi; e += 256) {
        int d = dst[e];
        int s = src[e];
        int pos = atomicAdd(&cur[d >> 9], 1);
        part_edges[pos] = ((unsigned)(d & 511) << 17) | (unsigned)s;
    }
}

// ---------- pass C: per-bucket counting sort -> row_ptr, dinv, ssrc ----------
__global__ __launch_bounds__(256) void k_bucket(const unsigned* __restrict__ part_edges,
                                                const int* __restrict__ bscan, int nPB,
                                                int N, int Npad, int* __restrict__ row_ptr,
                                                float* __restrict__ dinv,
                                                int* __restrict__ ssrc) {
    __shared__ int cnt[512];
    __shared__ int excl[512];
    __shared__ int wsum[4];
    int t = threadIdx.x;
    int b = blockIdx.x;
    int pb = bscan[b * nPB];
    int pe = bscan[(b + 1) * nPB];   // bscan[M] == E for the last bucket
    cnt[t] = 0; cnt[t + 256] = 0;
    __syncthreads();
    for (int e = pb + t; e < pe; e += 256)
        atomicAdd(&cnt[(part_edges[e] >> 17) & 511], 1);
    __syncthreads();
    int a0 = cnt[2 * t], a1 = cnt[2 * t + 1];
    int s = a0 + a1;
    int lane = t & 63, wv = t >> 6;
    int inc = s;
    for (int off = 1; off < 64; off <<= 1) {
        int u = __shfl_up(inc, off, 64);
        if (lane >= off) inc += u;
    }
    if (lane == 63) wsum[wv] = inc;
    __syncthreads();
    int pre = inc - s;
    for (int w = 0; w < wv; ++w) pre += wsum[w];
    excl[2 * t] = pre;
    excl[2 * t + 1] = pre + a0;
    int base = b << 9;
#pragma unroll
    for (int j = 0; j < 2; ++j) {
        int i = 2 * t + j;
        int g = base + i;
        int c = (j == 0) ? a0 : a1;
        int ex = (j == 0) ? pre : pre + a0;
        if (g < N) {
            row_ptr[g] = pb + ex;
            if (g == N - 1) row_ptr[N] = pb + ex + c;
        }
        if (g < Npad) dinv[g] = rsqrtf((float)c + 1.0f);
    }
    __syncthreads();
    for (int e = pb + t; e < pe; e += 256) {
        unsigned pk = part_edges[e];
        int doff = (pk >> 17) & 511;
        int pos = pb + atomicAdd(&excl[doff], 1);
        ssrc[pos] = (int)(pk & 0x1FFFFu);
    }
}

// ---------- conversions ----------
__global__ void k_cvt_x(const float4* __restrict__ x, ushort4* __restrict__ out, int n4) {
    int i = blockIdx.x * blockDim.x + threadIdx.x;
    if (i < n4) {
        float4 v = x[i];
        ushort4 o;
        o.x = f2bf(v.x); o.y = f2bf(v.y); o.z = f2bf(v.z); o.w = f2bf(v.w);
        out[i] = o;
    }
}

// W [K=128][realCols] f32 row-major -> fragment layout bf16:
// Wf[((kk*NT + n)*64 + lane)*8 + j] = W[kk*32 + (lane>>4)*8 + j][n*16 + (lane&15)]
__global__ void k_wfrag(const float* __restrict__ W, unsigned short* __restrict__ Wf,
                        int Ncol, int realCols) {
    int NT = Ncol >> 4;
    int total = 4 * NT * 64 * 8;
    int idx = blockIdx.x * blockDim.x + threadIdx.x;
    if (idx >= total) return;
    int j = idx & 7;
    int l = (idx >> 3) & 63;
    int t = idx >> 9;          // kk*NT + n
    int n = t % NT;
    int kk = t / NT;
    int k = kk * 32 + ((l >> 4) << 3) + j;
    int c = (n << 4) + (l & 15);
    float v = (c < realCols) ? W[k * realCols + c] : 0.0f;
    Wf[idx] = f2bf(v);
}

// ---------- GEMM: H'[Npad][NT*16] = dinv[row] * (A[Npad][128] @ W) ----------
template<int NT>
__global__ __launch_bounds__(256) void k_gemm(const unsigned short* __restrict__ A,
                                              const unsigned short* __restrict__ Wf,
                                              const float* __restrict__ dinv,
                                              unsigned short* __restrict__ Hout) {
    int lane = threadIdx.x & 63;
    int wv = threadIdx.x >> 6;
    int rb = blockIdx.x * 4 + wv;
    size_t row0 = (size_t)rb * 16;
    const unsigned short* arow = A + (row0 + (lane & 15)) * 128 + ((lane >> 4) << 3);
    f32x4 acc[NT];
#pragma unroll
    for (int n = 0; n < NT; ++n) acc[n] = (f32x4){0.f, 0.f, 0.f, 0.f};
#pragma unroll
    for (int kk = 0; kk < 4; ++kk) {
        bf16x8 a = *(const bf16x8*)(arow + kk * 32);
#pragma unroll
        for (int n = 0; n < NT; ++n) {
            bf16x8 b = *(const bf16x8*)(Wf + (((kk * NT + n) * 64 + lane) << 3));
            acc[n] = __builtin_amdgcn_mfma_f32_16x16x32_bf16(a, b, acc[n], 0, 0, 0);
        }
    }
    const int NCOL = NT * 16;
    size_t crow = row0 + ((lane >> 4) << 2);
    int ccol = lane & 15;
    float dv[4];
#pragma unroll
    for (int q = 0; q < 4; ++q) dv[q] = dinv[crow + q];
#pragma unroll
    for (int n = 0; n < NT; ++n) {
#pragma unroll
        for (int q = 0; q < 4; ++q) {
            Hout[(crow + q) * NCOL + n * 16 + ccol] = f2bf(acc[n][q] * dv[q]);
        }
    }
}

// ---------- aggregation (128 ch): Out[i] = relu(dinv[i]*(sum H'[src] + H'[i]) + b) ----------
__global__ __launch_bounds__(256) void k_agg(const unsigned short* __restrict__ H,
                                             const int* __restrict__ row_ptr,
                                             const int* __restrict__ ssrc,
                                             const float* __restrict__ dinv,
                                             const float* __restrict__ bias,
                                             unsigned short* __restrict__ Out, int N) {
    int lane = threadIdx.x & 63;
    int i = blockIdx.x * 4 + (threadIdx.x >> 6);
    if (i >= N) return;
    float dv = dinv[i];
    unsigned v = *(const unsigned*)(H + ((size_t)i << 7) + (lane << 1));
    float acc0 = bf2f((unsigned short)(v & 0xffff));
    float acc1 = bf2f((unsigned short)(v >> 16));
    int e = row_ptr[i], e1 = row_ptr[i + 1];
#pragma unroll 4
    for (; e < e1; ++e) {
        int s = ssrc[e];
        unsigned hv = *(const unsigned*)(H + ((size_t)s << 7) + (lane << 1));
        acc0 += bf2f((unsigned short)(hv & 0xffff));
        acc1 += bf2f((unsigned short)(hv >> 16));
    }
    acc0 = fmaxf(acc0 * dv + bias[lane * 2], 0.f);
    acc1 = fmaxf(acc1 * dv + bias[lane * 2 + 1], 0.f);
    unsigned o = (unsigned)f2bf(acc0) | ((unsigned)f2bf(acc1) << 16);
    *(unsigned*)(Out + ((size_t)i << 7) + (lane << 1)) = o;
}

// ---------- final aggregation (64-padded ch, Cout real) + bias + log_softmax ----------
__global__ __launch_bounds__(256) void k_agg3(const unsigned short* __restrict__ H,
                                              const int* __restrict__ row_ptr,
                                              const int* __restrict__ ssrc,
                                              const float* __restrict__ dinv,
                                              const float* __restrict__ b3,
                                              float* __restrict__ Out, int N, int Cout) {
    int lane = threadIdx.x & 63;
    int i = blockIdx.x * 4 + (threadIdx.x >> 6);
    if (i >= N) return;
    float dv = dinv[i];
    float acc = bf2f(H[((size_t)i << 6) + lane]);
    int e = row_ptr[i], e1 = row_ptr[i + 1];
#pragma unroll 4
    for (; e < e1; ++e) {
        int s = ssrc[e];
        acc += bf2f(H[((size_t)s << 6) + lane]);
    }
    float z = (lane < Cout) ? acc * dv + b3[lane] : -1e30f;
    float m = z;
    for (int off = 32; off; off >>= 1) m = fmaxf(m, __shfl_xor(m, off, 64));
    float p = (lane < Cout) ? expf(z - m) : 0.f;
    float ssum = p;
    for (int off = 32; off; off >>= 1) ssum += __shfl_xor(ssum, off, 64);
    if (lane < Cout) Out[(size_t)i * Cout + lane] = z - m - logf(ssum);
}

extern "C" void kernel_launch(void* const* d_in, const int* in_sizes, int n_in,
                              void* d_out, int out_size, void* d_ws, size_t ws_size,
                              hipStream_t stream) {
    const float* x  = (const float*)d_in[0];
    const int*   ei = (const int*)d_in[1];
    const float* W1 = (const float*)d_in[2];
    const float* b1 = (const float*)d_in[3];
    const float* W2 = (const float*)d_in[4];
    const float* b2 = (const float*)d_in[5];
    const float* W3 = (const float*)d_in[6];
    const float* b3 = (const float*)d_in[7];

    const int N = in_sizes[0] / 128;
    const int E = in_sizes[1] / 2;
    const int Cout = in_sizes[7];       // 47
    const int Npad = (N + 63) & ~63;
    const int* srcp = ei;
    const int* dstp = ei + E;

    const int NB  = (N + 511) >> 9;             // coarse buckets (196), must be <= 256
    const int nPB = (E + CHB - 1) / CHB;        // partition blocks (196)
    const int M   = NB * nPB;                   // bhist size (38416)

    // ---- workspace partition (256B aligned) ----
    char* p = (char*)d_ws;
    auto alloc = [&](size_t bytes) -> void* {
        void* r = (void*)p;
        p += (bytes + 255) & ~(size_t)255;
        return r;
    };
    float* dinv     = (float*)alloc((size_t)Npad * 4);
    int*   row_ptr  = (int*)alloc((size_t)(N + 1) * 4);
    int*   bhist    = (int*)alloc((size_t)M * 4);
    int*   bscan    = (int*)alloc((size_t)(M + 1) * 4);
    int*   part     = (int*)alloc(1024 * 4);
    unsigned* pedge = (unsigned*)alloc((size_t)E * 4);
    int*   ssrc     = (int*)alloc((size_t)E * 4);
    unsigned short* xb  = (unsigned short*)alloc((size_t)Npad * 128 * 2);
    unsigned short* hb  = (unsigned short*)alloc((size_t)Npad * 128 * 2);
    unsigned short* ab  = (unsigned short*)alloc((size_t)Npad * 128 * 2);
    unsigned short* wf1 = (unsigned short*)alloc(128 * 128 * 2);
    unsigned short* wf2 = (unsigned short*)alloc(128 * 128 * 2);
    unsigned short* wf3 = (unsigned short*)alloc(128 * 64 * 2);

    // ---- CSR build: hist -> scan -> partition -> per-bucket counting sort ----
    const int nb2 = (M + 1023) / 1024;          // 38 blocks (<= 256)
    k_hist<<<nPB, 256, 0, stream>>>(dstp, E, nPB, bhist, NB);
    k_scan_part<<<nb2, 256, 0, stream>>>(bhist, part, M);
    k_scan_mid<<<1, 256, 0, stream>>>(part, nb2);
    k_scan_final<<<nb2, 256, 0, stream>>>(bhist, part, bscan, M);
    k_partition<<<nPB, 256, 0, stream>>>(srcp, dstp, E, nPB, bscan, pedge, NB);
    k_bucket<<<NB, 256, 0, stream>>>(pedge, bscan, nPB, N, Npad, row_ptr, dinv, ssrc);

    // conversions
    k_cvt_x<<<(N * 128 / 4 + 255) / 256, 256, 0, stream>>>((const float4*)x, (ushort4*)xb,
                                                           N * 128 / 4);
    k_wfrag<<<(16384 + 255) / 256, 256, 0, stream>>>(W1, wf1, 128, 128);
    k_wfrag<<<(16384 + 255) / 256, 256, 0, stream>>>(W2, wf2, 128, 128);
    k_wfrag<<<(8192 + 255) / 256, 256, 0, stream>>>(W3, wf3, 64, Cout);

    const int gemmGrid = Npad / 64;
    const int aggGrid = (N + 3) / 4;

    // layer 1
    k_gemm<8><<<gemmGrid, 256, 0, stream>>>(xb, wf1, dinv, hb);
    k_agg<<<aggGrid, 256, 0, stream>>>(hb, row_ptr, ssrc, dinv, b1, ab, N);
    // layer 2
    k_gemm<8><<<gemmGrid, 256, 0, stream>>>(ab, wf2, dinv, hb);
    k_agg<<<aggGrid, 256, 0, stream>>>(hb, row_ptr, ssrc, dinv, b2, ab, N);
    // layer 3 (output padded to 64 cols) + log_softmax
    k_gemm<4><<<gemmGrid, 256, 0, stream>>>(ab, wf3, dinv, hb);
    k_agg3<<<aggGrid, 256, 0, stream>>>(hb, row_ptr, ssrc, dinv, b3,
                                        (float*)d_out, N, Cout);
}

// Round 5
// 330.221 us; speedup vs baseline: 1.4885x; 1.0039x over previous
//
#include <hip/hip_runtime.h>
#include <stdint.h>

typedef __bf16 bf16x8 __attribute__((ext_vector_type(8)));
typedef float f32x4 __attribute__((ext_vector_type(4)));

#define CHB 8192  // edges per partition block

__device__ __forceinline__ float bf2f(unsigned short s) {
    union { unsigned u; float f; } x; x.u = ((unsigned)s) << 16; return x.f;
}
__device__ __forceinline__ float bitf(unsigned u) {
    union { unsigned u; float f; } x; x.u = u; return x.f;
}
__device__ __forceinline__ unsigned short f2bf(float f) {
    union { float f; unsigned u; } x; x.f = f;
    unsigned r = x.u + 0x7fffu + ((x.u >> 16) & 1u);
    return (unsigned short)(r >> 16);
}

// ---------- pass A: per-(bucket,block) histogram. bucket = dst>>9 ----------
__global__ __launch_bounds__(256) void k_hist(const int* __restrict__ dst, int E, int nPB,
                                              int* __restrict__ bhist, int NB) {
    __shared__ int h[256];
    int t = threadIdx.x;
    h[t] = 0;
    __syncthreads();
    int blk = blockIdx.x;
    int hi = min((blk + 1) * CHB, E);
    for (int e = blk * CHB + t; e < hi; e += 256) atomicAdd(&h[dst[e] >> 9], 1);
    __syncthreads();
    if (t < NB) bhist[t * nPB + blk] = h[t];
}

// ---------- hierarchical scan (generic): in[M] -> out[M+1] exclusive ----------
__global__ __launch_bounds__(256) void k_scan_part(const int* __restrict__ deg,
                                                   int* __restrict__ part, int N) {
    __shared__ int wsum[4];
    int t = threadIdx.x;
    int lane = t & 63, wv = t >> 6;
    int base = blockIdx.x * 1024 + t * 4;
    int s = 0;
#pragma unroll
    for (int j = 0; j < 4; ++j) {
        int i = base + j;
        if (i < N) s += deg[i];
    }
    for (int off = 1; off < 64; off <<= 1) s += __shfl_xor(s, off, 64);
    if (lane == 0) wsum[wv] = s;
    __syncthreads();
    if (t == 0) part[blockIdx.x] = wsum[0] + wsum[1] + wsum[2] + wsum[3];
}

__global__ void k_scan_mid(int* __restrict__ part, int nb) {
    __shared__ int buf[256];
    int t = threadIdx.x;
    buf[t] = (t < nb) ? part[t] : 0;
    __syncthreads();
    for (int off = 1; off < 256; off <<= 1) {
        int v = buf[t];
        int u = (t >= off) ? buf[t - off] : 0;
        __syncthreads();
        buf[t] = v + u;
        __syncthreads();
    }
    if (t < nb) part[t] = (t == 0) ? 0 : buf[t - 1];
}

__global__ __launch_bounds__(256) void k_scan_final(const int* __restrict__ deg,
                                                    const int* __restrict__ part,
                                                    int* __restrict__ out, int N) {
    __shared__ int wsum[4];
    int t = threadIdx.x;
    int lane = t & 63, wv = t >> 6;
    int base = blockIdx.x * 1024 + t * 4;
    int v[4];
    int s = 0;
#pragma unroll
    for (int j = 0; j < 4; ++j) {
        int i = base + j;
        v[j] = (i < N) ? deg[i] : 0;
        s += v[j];
    }
    int inc = s;
    for (int off = 1; off < 64; off <<= 1) {
        int u = __shfl_up(inc, off, 64);
        if (lane >= off) inc += u;
    }
    if (lane == 63) wsum[wv] = inc;
    __syncthreads();
    int excl = part[blockIdx.x] + inc - s;
    for (int w = 0; w < wv; ++w) excl += wsum[w];
#pragma unroll
    for (int j = 0; j < 4; ++j) {
        int i = base + j;
        if (i < N) {
            out[i] = excl;
            excl += v[j];
            if (i == N - 1) out[N] = excl;
        }
    }
}

// ---------- pass B: partition edges into bucket-contiguous regions ----------
__global__ __launch_bounds__(256) void k_partition(const int* __restrict__ src,
                                                   const int* __restrict__ dst, int E,
                                                   int nPB, const int* __restrict__ bscan,
                                                   unsigned* __restrict__ part_edges, int NB) {
    __shared__ int cur[256];
    int t = threadIdx.x;
    int blk = blockIdx.x;
    if (t < NB) cur[t] = bscan[t * nPB + blk];
    __syncthreads();
    int hi = min((blk + 1) * CHB, E);
    for (int e = blk * CHB + t; e < hi; e += 256) {
        int d = dst[e];
        int s = src[e];
        int pos = atomicAdd(&cur[d >> 9], 1);
        part_edges[pos] = ((unsigned)(d & 511) << 17) | (unsigned)s;
    }
}

// ---------- pass C: per-bucket counting sort -> row_ptr, dinv, ssrc ----------
__global__ __launch_bounds__(256) void k_bucket(const unsigned* __restrict__ part_edges,
                                                const int* __restrict__ bscan, int nPB,
                                                int N, int Npad, int* __restrict__ row_ptr,
                                                float* __restrict__ dinv,
                                                int* __restrict__ ssrc) {
    __shared__ int cnt[512];
    __shared__ int excl[512];
    __shared__ int wsum[4];
    int t = threadIdx.x;
    int b = blockIdx.x;
    int pb = bscan[b * nPB];
    int pe = bscan[(b + 1) * nPB];   // bscan[M] == E for the last bucket
    cnt[t] = 0; cnt[t + 256] = 0;
    __syncthreads();
    for (int e = pb + t; e < pe; e += 256)
        atomicAdd(&cnt[(part_edges[e] >> 17) & 511], 1);
    __syncthreads();
    int a0 = cnt[2 * t], a1 = cnt[2 * t + 1];
    int s = a0 + a1;
    int lane = t & 63, wv = t >> 6;
    int inc = s;
    for (int off = 1; off < 64; off <<= 1) {
        int u = __shfl_up(inc, off, 64);
        if (lane >= off) inc += u;
    }
    if (lane == 63) wsum[wv] = inc;
    __syncthreads();
    int pre = inc - s;
    for (int w = 0; w < wv; ++w) pre += wsum[w];
    excl[2 * t] = pre;
    excl[2 * t + 1] = pre + a0;
    int base = b << 9;
#pragma unroll
    for (int j = 0; j < 2; ++j) {
        int i = 2 * t + j;
        int g = base + i;
        int c = (j == 0) ? a0 : a1;
        int ex = (j == 0) ? pre : pre + a0;
        if (g < N) {
            row_ptr[g] = pb + ex;
            if (g == N - 1) row_ptr[N] = pb + ex + c;
        }
        if (g < Npad) dinv[g] = rsqrtf((float)c + 1.0f);
    }
    __syncthreads();
    for (int e = pb + t; e < pe; e += 256) {
        unsigned pk = part_edges[e];
        int doff = (pk >> 17) & 511;
        int pos = pb + atomicAdd(&excl[doff], 1);
        ssrc[pos] = (int)(pk & 0x1FFFFu);
    }
}

// ---------- conversions ----------
__global__ void k_cvt_x(const float4* __restrict__ x, ushort4* __restrict__ out, int n4) {
    int i = blockIdx.x * blockDim.x + threadIdx.x;
    if (i < n4) {
        float4 v = x[i];
        ushort4 o;
        o.x = f2bf(v.x); o.y = f2bf(v.y); o.z = f2bf(v.z); o.w = f2bf(v.w);
        out[i] = o;
    }
}

// W [K=128][realCols] f32 row-major -> fragment layout bf16:
// Wf[((kk*NT + n)*64 + lane)*8 + j] = W[kk*32 + (lane>>4)*8 + j][n*16 + (lane&15)]
__global__ void k_wfrag(const float* __restrict__ W, unsigned short* __restrict__ Wf,
                        int Ncol, int realCols) {
    int NT = Ncol >> 4;
    int total = 4 * NT * 64 * 8;
    int idx = blockIdx.x * blockDim.x + threadIdx.x;
    if (idx >= total) return;
    int j = idx & 7;
    int l = (idx >> 3) & 63;
    int t = idx >> 9;          // kk*NT + n
    int n = t % NT;
    int kk = t / NT;
    int k = kk * 32 + ((l >> 4) << 3) + j;
    int c = (n << 4) + (l & 15);
    float v = (c < realCols) ? W[k * realCols + c] : 0.0f;
    Wf[idx] = f2bf(v);
}

// ---------- GEMM: H'[Npad][NT*16] = dinv[row] * (A[Npad][128] @ W) ----------
template<int NT>
__global__ __launch_bounds__(256) void k_gemm(const unsigned short* __restrict__ A,
                                              const unsigned short* __restrict__ Wf,
                                              const float* __restrict__ dinv,
                                              unsigned short* __restrict__ Hout) {
    int lane = threadIdx.x & 63;
    int wv = threadIdx.x >> 6;
    int rb = blockIdx.x * 4 + wv;
    size_t row0 = (size_t)rb * 16;
    const unsigned short* arow = A + (row0 + (lane & 15)) * 128 + ((lane >> 4) << 3);
    f32x4 acc[NT];
#pragma unroll
    for (int n = 0; n < NT; ++n) acc[n] = (f32x4){0.f, 0.f, 0.f, 0.f};
#pragma unroll
    for (int kk = 0; kk < 4; ++kk) {
        bf16x8 a = *(const bf16x8*)(arow + kk * 32);
#pragma unroll
        for (int n = 0; n < NT; ++n) {
            bf16x8 b = *(const bf16x8*)(Wf + (((kk * NT + n) * 64 + lane) << 3));
            acc[n] = __builtin_amdgcn_mfma_f32_16x16x32_bf16(a, b, acc[n], 0, 0, 0);
        }
    }
    const int NCOL = NT * 16;
    size_t crow = row0 + ((lane >> 4) << 2);
    int ccol = lane & 15;
    float dv[4];
#pragma unroll
    for (int q = 0; q < 4; ++q) dv[q] = dinv[crow + q];
#pragma unroll
    for (int n = 0; n < NT; ++n) {
#pragma unroll
        for (int q = 0; q < 4; ++q) {
            Hout[(crow + q) * NCOL + n * 16 + ccol] = f2bf(acc[n][q] * dv[q]);
        }
    }
}

// ---------- aggregation (128 ch): one wave per dst node ----------
// 4 groups x 16 lanes; group g gathers edge (j+g) with dwordx4 (8 ch/lane);
// cross-group shfl_xor reduce at the end. Out[i] = relu(dinv[i]*(sum+self)+b)
__global__ __launch_bounds__(256) void k_agg(const unsigned short* __restrict__ H,
                                             const int* __restrict__ row_ptr,
                                             const int* __restrict__ ssrc,
                                             const float* __restrict__ dinv,
                                             const float* __restrict__ bias,
                                             unsigned short* __restrict__ Out, int N) {
    int lane = threadIdx.x & 63;
    int i = blockIdx.x * 4 + (threadIdx.x >> 6);
    if (i >= N) return;
    int g = lane >> 4;
    int c16 = lane & 15;                    // 16B chunk within the 256B row
    const uint4* Hv = (const uint4*)H;      // row i = 16 uint4
    float acc[8];
#pragma unroll
    for (int c = 0; c < 8; ++c) acc[c] = 0.f;
    int e0 = row_ptr[i], e1 = row_ptr[i + 1];
    for (int base = e0; base < e1; base += 64) {
        int cnt = min(64, e1 - base);
        int sidx = (lane < cnt) ? ssrc[base + lane] : 0;
        for (int j = 0; j < cnt; j += 4) {
            int jj = j + g;
            int s = __shfl(sidx, jj, 64);
            if (jj < cnt) {
                uint4 v = Hv[((size_t)s << 4) + c16];
                acc[0] += bitf(v.x << 16); acc[1] += bitf(v.x & 0xffff0000u);
                acc[2] += bitf(v.y << 16); acc[3] += bitf(v.y & 0xffff0000u);
                acc[4] += bitf(v.z << 16); acc[5] += bitf(v.z & 0xffff0000u);
                acc[6] += bitf(v.w << 16); acc[7] += bitf(v.w & 0xffff0000u);
            }
        }
    }
    if (g == 0) {   // self row, added exactly once
        uint4 v = Hv[((size_t)i << 4) + c16];
        acc[0] += bitf(v.x << 16); acc[1] += bitf(v.x & 0xffff0000u);
        acc[2] += bitf(v.y << 16); acc[3] += bitf(v.y & 0xffff0000u);
        acc[4] += bitf(v.z << 16); acc[5] += bitf(v.z & 0xffff0000u);
        acc[6] += bitf(v.w << 16); acc[7] += bitf(v.w & 0xffff0000u);
    }
#pragma unroll
    for (int c = 0; c < 8; ++c) {
        acc[c] += __shfl_xor(acc[c], 16, 64);
        acc[c] += __shfl_xor(acc[c], 32, 64);
    }
    if (g == 0) {
        float dv = dinv[i];
        const float4* bv = (const float4*)bias;
        float4 b0 = bv[c16 * 2], b1 = bv[c16 * 2 + 1];
        float r0 = fmaxf(acc[0] * dv + b0.x, 0.f);
        float r1 = fmaxf(acc[1] * dv + b0.y, 0.f);
        float r2 = fmaxf(acc[2] * dv + b0.z, 0.f);
        float r3 = fmaxf(acc[3] * dv + b0.w, 0.f);
        float r4 = fmaxf(acc[4] * dv + b1.x, 0.f);
        float r5 = fmaxf(acc[5] * dv + b1.y, 0.f);
        float r6 = fmaxf(acc[6] * dv + b1.z, 0.f);
        float r7 = fmaxf(acc[7] * dv + b1.w, 0.f);
        uint4 o;
        o.x = (unsigned)f2bf(r0) | ((unsigned)f2bf(r1) << 16);
        o.y = (unsigned)f2bf(r2) | ((unsigned)f2bf(r3) << 16);
        o.z = (unsigned)f2bf(r4) | ((unsigned)f2bf(r5) << 16);
        o.w = (unsigned)f2bf(r6) | ((unsigned)f2bf(r7) << 16);
        ((uint4*)Out)[((size_t)i << 4) + c16] = o;
    }
}

// ---------- final aggregation (64ch padded, Cout real) + bias + log_softmax ----------
// 8 groups x 8 lanes; group g gathers edge (j+g) with dwordx4.
__global__ __launch_bounds__(256) void k_agg3(const unsigned short* __restrict__ H,
                                              const int* __restrict__ row_ptr,
                                              const int* __restrict__ ssrc,
                                              const float* __restrict__ dinv,
                                              const float* __restrict__ b3,
                                              float* __restrict__ Out, int N, int Cout) {
    int lane = threadIdx.x & 63;
    int i = blockIdx.x * 4 + (threadIdx.x >> 6);
    if (i >= N) return;
    int g = lane >> 3;
    int c8 = lane & 7;                      // 16B chunk within the 128B row
    const uint4* Hv = (const uint4*)H;      // row i = 8 uint4
    float acc[8];
#pragma unroll
    for (int c = 0; c < 8; ++c) acc[c] = 0.f;
    int e0 = row_ptr[i], e1 = row_ptr[i + 1];
    for (int base = e0; base < e1; base += 64) {
        int cnt = min(64, e1 - base);
        int sidx = (lane < cnt) ? ssrc[base + lane] : 0;
        for (int j = 0; j < cnt; j += 8) {
            int jj = j + g;
            int s = __shfl(sidx, jj, 64);
            if (jj < cnt) {
                uint4 v = Hv[((size_t)s << 3) + c8];
                acc[0] += bitf(v.x << 16); acc[1] += bitf(v.x & 0xffff0000u);
                acc[2] += bitf(v.y << 16); acc[3] += bitf(v.y & 0xffff0000u);
                acc[4] += bitf(v.z << 16); acc[5] += bitf(v.z & 0xffff0000u);
                acc[6] += bitf(v.w << 16); acc[7] += bitf(v.w & 0xffff0000u);
            }
        }
    }
    if (g == 0) {
        uint4 v = Hv[((size_t)i << 3) + c8];
        acc[0] += bitf(v.x << 16); acc[1] += bitf(v.x & 0xffff0000u);
        acc[2] += bitf(v.y << 16); acc[3] += bitf(v.y & 0xffff0000u);
        acc[4] += bitf(v.z << 16); acc[5] += bitf(v.z & 0xffff0000u);
        acc[6] += bitf(v.w << 16); acc[7] += bitf(v.w & 0xffff0000u);
    }
#pragma unroll
    for (int c = 0; c < 8; ++c) {
        acc[c] += __shfl_xor(acc[c], 8, 64);
        acc[c] += __shfl_xor(acc[c], 16, 64);
        acc[c] += __shfl_xor(acc[c], 32, 64);
    }
    float dv = dinv[i];
    float z[8];
    float m = -1e30f;
#pragma unroll
    for (int c = 0; c < 8; ++c) {
        int ch = c8 * 8 + c;
        z[c] = (ch < Cout) ? acc[c] * dv + b3[ch] : -1e30f;
        m = fmaxf(m, z[c]);
    }
    for (int off = 1; off < 8; off <<= 1) m = fmaxf(m, __shfl_xor(m, off, 64));
    float ssum = 0.f;
#pragma unroll
    for (int c = 0; c < 8; ++c) {
        int ch = c8 * 8 + c;
        if (ch < Cout) ssum += expf(z[c] - m);
    }
    for (int off = 1; off < 8; off <<= 1) ssum += __shfl_xor(ssum, off, 64);
    if (g == 0) {
        float lg = m + logf(ssum);
#pragma unroll
        for (int c = 0; c < 8; ++c) {
            int ch = c8 * 8 + c;
            if (ch < Cout) Out[(size_t)i * Cout + ch] = z[c] - lg;
        }
    }
}

extern "C" void kernel_launch(void* const* d_in, const int* in_sizes, int n_in,
                              void* d_out, int out_size, void* d_ws, size_t ws_size,
                              hipStream_t stream) {
    const float* x  = (const float*)d_in[0];
    const int*   ei = (const int*)d_in[1];
    const float* W1 = (const float*)d_in[2];
    const float* b1 = (const float*)d_in[3];
    const float* W2 = (const float*)d_in[4];
    const float* b2 = (const float*)d_in[5];
    const float* W3 = (const float*)d_in[6];
    const float* b3 = (const float*)d_in[7];

    const int N = in_sizes[0] / 128;
    const int E = in_sizes[1] / 2;
    const int Cout = in_sizes[7];       // 47
    const int Npad = (N + 63) & ~63;
    const int* srcp = ei;
    const int* dstp = ei + E;

    const int NB  = (N + 511) >> 9;             // coarse buckets (196), must be <= 256
    const int nPB = (E + CHB - 1) / CHB;        // partition blocks (196)
    const int M   = NB * nPB;                   // bhist size (38416)

    // ---- workspace partition (256B aligned) ----
    char* p = (char*)d_ws;
    auto alloc = [&](size_t bytes) -> void* {
        void* r = (void*)p;
        p += (bytes + 255) & ~(size_t)255;
        return r;
    };
    float* dinv     = (float*)alloc((size_t)Npad * 4);
    int*   row_ptr  = (int*)alloc((size_t)(N + 1) * 4);
    int*   bhist    = (int*)alloc((size_t)M * 4);
    int*   bscan    = (int*)alloc((size_t)(M + 1) * 4);
    int*   part     = (int*)alloc(1024 * 4);
    unsigned* pedge = (unsigned*)alloc((size_t)E * 4);
    int*   ssrc     = (int*)alloc((size_t)E * 4);
    unsigned short* xb  = (unsigned short*)alloc((size_t)Npad * 128 * 2);
    unsigned short* hb  = (unsigned short*)alloc((size_t)Npad * 128 * 2);
    unsigned short* ab  = (unsigned short*)alloc((size_t)Npad * 128 * 2);
    unsigned short* wf1 = (unsigned short*)alloc(128 * 128 * 2);
    unsigned short* wf2 = (unsigned short*)alloc(128 * 128 * 2);
    unsigned short* wf3 = (unsigned short*)alloc(128 * 64 * 2);

    // ---- CSR build: hist -> scan -> partition -> per-bucket counting sort ----
    const int nb2 = (M + 1023) / 1024;          // 38 blocks (<= 256)
    k_hist<<<nPB, 256, 0, stream>>>(dstp, E, nPB, bhist, NB);
    k_scan_part<<<nb2, 256, 0, stream>>>(bhist, part, M);
    k_scan_mid<<<1, 256, 0, stream>>>(part, nb2);
    k_scan_final<<<nb2, 256, 0, stream>>>(bhist, part, bscan, M);
    k_partition<<<nPB, 256, 0, stream>>>(srcp, dstp, E, nPB, bscan, pedge, NB);
    k_bucket<<<NB, 256, 0, stream>>>(pedge, bscan, nPB, N, Npad, row_ptr, dinv, ssrc);

    // conversions
    k_cvt_x<<<(N * 128 / 4 + 255) / 256, 256, 0, stream>>>((const float4*)x, (ushort4*)xb,
                                                           N * 128 / 4);
    k_wfrag<<<(16384 + 255) / 256, 256, 0, stream>>>(W1, wf1, 128, 128);
    k_wfrag<<<(16384 + 255) / 256, 256, 0, stream>>>(W2, wf2, 128, 128);
    k_wfrag<<<(8192 + 255) / 256, 256, 0, stream>>>(W3, wf3, 64, Cout);

    const int gemmGrid = Npad / 64;
    const int aggGrid = (N + 3) / 4;

    // layer 1
    k_gemm<8><<<gemmGrid, 256, 0, stream>>>(xb, wf1, dinv, hb);
    k_agg<<<aggGrid, 256, 0, stream>>>(hb, row_ptr, ssrc, dinv, b1, ab, N);
    // layer 2
    k_gemm<8><<<gemmGrid, 256, 0, stream>>>(ab, wf2, dinv, hb);
    k_agg<<<aggGrid, 256, 0, stream>>>(hb, row_ptr, ssrc, dinv, b2, ab, N);
    // layer 3 (output padded to 64 cols) + log_softmax
    k_gemm<4><<<gemmGrid, 256, 0, stream>>>(ab, wf3, dinv, hb);
    k_agg3<<<aggGrid, 256, 0, stream>>>(hb, row_ptr, ssrc, dinv, b3,
                                        (float*)d_out, N, Cout);
}

// Round 6
// 304.469 us; speedup vs baseline: 1.6144x; 1.0846x over previous
//
#include <hip/hip_runtime.h>
#include <stdint.h>

typedef __bf16 bf16x8 __attribute__((ext_vector_type(8)));
typedef float f32x4 __attribute__((ext_vector_type(4)));

#define CHB 8192  // edges per partition block

__device__ __forceinline__ float bf2f(unsigned short s) {
    union { unsigned u; float f; } x; x.u = ((unsigned)s) << 16; return x.f;
}
__device__ __forceinline__ float bitf(unsigned u) {
    union { unsigned u; float f; } x; x.u = u; return x.f;
}
__device__ __forceinline__ unsigned short f2bf(float f) {
    union { float f; unsigned u; } x; x.f = f;
    unsigned r = x.u + 0x7fffu + ((x.u >> 16) & 1u);
    return (unsigned short)(r >> 16);
}

// ---------- pass A: per-(bucket,block) histogram. bucket = dst>>9 ----------
__global__ __launch_bounds__(256) void k_hist(const int* __restrict__ dst, int E, int nPB,
                                              int* __restrict__ bhist, int NB) {
    __shared__ int h[256];
    int t = threadIdx.x;
    h[t] = 0;
    __syncthreads();
    int blk = blockIdx.x;
    int hi = min((blk + 1) * CHB, E);
    for (int e = blk * CHB + t; e < hi; e += 256) atomicAdd(&h[dst[e] >> 9], 1);
    __syncthreads();
    if (t < NB) bhist[t * nPB + blk] = h[t];
}

// ---------- hierarchical scan (generic): in[M] -> out[M+1] exclusive ----------
__global__ __launch_bounds__(256) void k_scan_part(const int* __restrict__ deg,
                                                   int* __restrict__ part, int N) {
    __shared__ int wsum[4];
    int t = threadIdx.x;
    int lane = t & 63, wv = t >> 6;
    int base = blockIdx.x * 1024 + t * 4;
    int s = 0;
#pragma unroll
    for (int j = 0; j < 4; ++j) {
        int i = base + j;
        if (i < N) s += deg[i];
    }
    for (int off = 1; off < 64; off <<= 1) s += __shfl_xor(s, off, 64);
    if (lane == 0) wsum[wv] = s;
    __syncthreads();
    if (t == 0) part[blockIdx.x] = wsum[0] + wsum[1] + wsum[2] + wsum[3];
}

__global__ void k_scan_mid(int* __restrict__ part, int nb) {
    __shared__ int buf[256];
    int t = threadIdx.x;
    buf[t] = (t < nb) ? part[t] : 0;
    __syncthreads();
    for (int off = 1; off < 256; off <<= 1) {
        int v = buf[t];
        int u = (t >= off) ? buf[t - off] : 0;
        __syncthreads();
        buf[t] = v + u;
        __syncthreads();
    }
    if (t < nb) part[t] = (t == 0) ? 0 : buf[t - 1];
}

__global__ __launch_bounds__(256) void k_scan_final(const int* __restrict__ deg,
                                                    const int* __restrict__ part,
                                                    int* __restrict__ out, int N) {
    __shared__ int wsum[4];
    int t = threadIdx.x;
    int lane = t & 63, wv = t >> 6;
    int base = blockIdx.x * 1024 + t * 4;
    int v[4];
    int s = 0;
#pragma unroll
    for (int j = 0; j < 4; ++j) {
        int i = base + j;
        v[j] = (i < N) ? deg[i] : 0;
        s += v[j];
    }
    int inc = s;
    for (int off = 1; off < 64; off <<= 1) {
        int u = __shfl_up(inc, off, 64);
        if (lane >= off) inc += u;
    }
    if (lane == 63) wsum[wv] = inc;
    __syncthreads();
    int excl = part[blockIdx.x] + inc - s;
    for (int w = 0; w < wv; ++w) excl += wsum[w];
#pragma unroll
    for (int j = 0; j < 4; ++j) {
        int i = base + j;
        if (i < N) {
            out[i] = excl;
            excl += v[j];
            if (i == N - 1) out[N] = excl;
        }
    }
}

// ---------- pass B: partition edges into bucket-contiguous regions ----------
__global__ __launch_bounds__(256) void k_partition(const int* __restrict__ src,
                                                   const int* __restrict__ dst, int E,
                                                   int nPB, const int* __restrict__ bscan,
                                                   unsigned* __restrict__ part_edges, int NB) {
    __shared__ int cur[256];
    int t = threadIdx.x;
    int blk = blockIdx.x;
    if (t < NB) cur[t] = bscan[t * nPB + blk];
    __syncthreads();
    int hi = min((blk + 1) * CHB, E);
    for (int e = blk * CHB + t; e < hi; e += 256) {
        int d = dst[e];
        int s = src[e];
        int pos = atomicAdd(&cur[d >> 9], 1);
        part_edges[pos] = ((unsigned)(d & 511) << 17) | (unsigned)s;
    }
}

// ---------- pass C: per-bucket counting sort -> row_ptr, dinv, ssrc ----------
__global__ __launch_bounds__(256) void k_bucket(const unsigned* __restrict__ part_edges,
                                                const int* __restrict__ bscan, int nPB,
                                                int N, int Npad, int* __restrict__ row_ptr,
                                                float* __restrict__ dinv,
                                                int* __restrict__ ssrc) {
    __shared__ int cnt[512];
    __shared__ int excl[512];
    __shared__ int wsum[4];
    int t = threadIdx.x;
    int b = blockIdx.x;
    int pb = bscan[b * nPB];
    int pe = bscan[(b + 1) * nPB];   // bscan[M] == E for the last bucket
    cnt[t] = 0; cnt[t + 256] = 0;
    __syncthreads();
    for (int e = pb + t; e < pe; e += 256)
        atomicAdd(&cnt[(part_edges[e] >> 17) & 511], 1);
    __syncthreads();
    int a0 = cnt[2 * t], a1 = cnt[2 * t + 1];
    int s = a0 + a1;
    int lane = t & 63, wv = t >> 6;
    int inc = s;
    for (int off = 1; off < 64; off <<= 1) {
        int u = __shfl_up(inc, off, 64);
        if (lane >= off) inc += u;
    }
    if (lane == 63) wsum[wv] = inc;
    __syncthreads();
    int pre = inc - s;
    for (int w = 0; w < wv; ++w) pre += wsum[w];
    excl[2 * t] = pre;
    excl[2 * t + 1] = pre + a0;
    int base = b << 9;
#pragma unroll
    for (int j = 0; j < 2; ++j) {
        int i = 2 * t + j;
        int g = base + i;
        int c = (j == 0) ? a0 : a1;
        int ex = (j == 0) ? pre : pre + a0;
        if (g < N) {
            row_ptr[g] = pb + ex;
            if (g == N - 1) row_ptr[N] = pb + ex + c;
        }
        if (g < Npad) dinv[g] = rsqrtf((float)c + 1.0f);
    }
    __syncthreads();
    for (int e = pb + t; e < pe; e += 256) {
        unsigned pk = part_edges[e];
        int doff = (pk >> 17) & 511;
        int pos = pb + atomicAdd(&excl[doff], 1);
        ssrc[pos] = (int)(pk & 0x1FFFFu);
    }
}

// ---------- conversions ----------
__global__ void k_cvt_x(const float4* __restrict__ x, ushort4* __restrict__ out, int n4) {
    int i = blockIdx.x * blockDim.x + threadIdx.x;
    if (i < n4) {
        float4 v = x[i];
        ushort4 o;
        o.x = f2bf(v.x); o.y = f2bf(v.y); o.z = f2bf(v.z); o.w = f2bf(v.w);
        out[i] = o;
    }
}

// W [K=128][realCols] f32 row-major -> fragment layout bf16:
// Wf[((kk*NT + n)*64 + lane)*8 + j] = W[kk*32 + (lane>>4)*8 + j][n*16 + (lane&15)]
__global__ void k_wfrag(const float* __restrict__ W, unsigned short* __restrict__ Wf,
                        int Ncol, int realCols) {
    int NT = Ncol >> 4;
    int total = 4 * NT * 64 * 8;
    int idx = blockIdx.x * blockDim.x + threadIdx.x;
    if (idx >= total) return;
    int j = idx & 7;
    int l = (idx >> 3) & 63;
    int t = idx >> 9;          // kk*NT + n
    int n = t % NT;
    int kk = t / NT;
    int k = kk * 32 + ((l >> 4) << 3) + j;
    int c = (n << 4) + (l & 15);
    float v = (c < realCols) ? W[k * realCols + c] : 0.0f;
    Wf[idx] = f2bf(v);
}

// ---------- GEMM: H'[Npad][NT*16] = dinv[row] * (A[Npad][128] @ W) ----------
template<int NT>
__global__ __launch_bounds__(256) void k_gemm(const unsigned short* __restrict__ A,
                                              const unsigned short* __restrict__ Wf,
                                              const float* __restrict__ dinv,
                                              unsigned short* __restrict__ Hout) {
    int lane = threadIdx.x & 63;
    int wv = threadIdx.x >> 6;
    int rb = blockIdx.x * 4 + wv;
    size_t row0 = (size_t)rb * 16;
    const unsigned short* arow = A + (row0 + (lane & 15)) * 128 + ((lane >> 4) << 3);
    f32x4 acc[NT];
#pragma unroll
    for (int n = 0; n < NT; ++n) acc[n] = (f32x4){0.f, 0.f, 0.f, 0.f};
#pragma unroll
    for (int kk = 0; kk < 4; ++kk) {
        bf16x8 a = *(const bf16x8*)(arow + kk * 32);
#pragma unroll
        for (int n = 0; n < NT; ++n) {
            bf16x8 b = *(const bf16x8*)(Wf + (((kk * NT + n) * 64 + lane) << 3));
            acc[n] = __builtin_amdgcn_mfma_f32_16x16x32_bf16(a, b, acc[n], 0, 0, 0);
        }
    }
    const int NCOL = NT * 16;
    size_t crow = row0 + ((lane >> 4) << 2);
    int ccol = lane & 15;
    float dv[4];
#pragma unroll
    for (int q = 0; q < 4; ++q) dv[q] = dinv[crow + q];
#pragma unroll
    for (int n = 0; n < NT; ++n) {
#pragma unroll
        for (int q = 0; q < 4; ++q) {
            Hout[(crow + q) * NCOL + n * 16 + ccol] = f2bf(acc[n][q] * dv[q]);
        }
    }
}

#define UNPACK8(v)                                                          \
    acc[0] += bitf((v).x << 16); acc[1] += bitf((v).x & 0xffff0000u);       \
    acc[2] += bitf((v).y << 16); acc[3] += bitf((v).y & 0xffff0000u);       \
    acc[4] += bitf((v).z << 16); acc[5] += bitf((v).z & 0xffff0000u);       \
    acc[6] += bitf((v).w << 16); acc[7] += bitf((v).w & 0xffff0000u);

#define UNPACK4(v)                                                          \
    acc[0] += bitf((v).x << 16); acc[1] += bitf((v).x & 0xffff0000u);       \
    acc[2] += bitf((v).y << 16); acc[3] += bitf((v).y & 0xffff0000u);

// ---------- aggregation (128 ch): one wave per dst node ----------
// 4 groups x 16 lanes; group g gathers edge (j+g) with dwordx4 (8 ch/lane);
// guard-free main loop + tail; cross-group shfl_xor reduce at the end.
__global__ __launch_bounds__(256) void k_agg(const unsigned short* __restrict__ H,
                                             const int* __restrict__ row_ptr,
                                             const int* __restrict__ ssrc,
                                             const float* __restrict__ dinv,
                                             const float* __restrict__ bias,
                                             unsigned short* __restrict__ Out, int N) {
    int lane = threadIdx.x & 63;
    int i = blockIdx.x * 4 + (threadIdx.x >> 6);
    if (i >= N) return;
    int g = lane >> 4;
    int c16 = lane & 15;                    // 16B chunk within the 256B row
    const uint4* Hv = (const uint4*)H;      // row i = 16 uint4
    float acc[8];
#pragma unroll
    for (int c = 0; c < 8; ++c) acc[c] = 0.f;
    int e0 = row_ptr[i], e1 = row_ptr[i + 1];
    for (int base = e0; base < e1; base += 64) {
        int cnt = min(64, e1 - base);
        int sidx = (lane < cnt) ? ssrc[base + lane] : 0;
        int full = cnt & ~3;
#pragma unroll 2
        for (int j = 0; j < full; j += 4) {
            int s = __shfl(sidx, j + g, 64);
            uint4 v = Hv[((size_t)s << 4) + c16];
            UNPACK8(v);
        }
        int jj = full + g;
        if (jj < cnt) {
            int s = __shfl(sidx, jj, 64);
            uint4 v = Hv[((size_t)s << 4) + c16];
            UNPACK8(v);
        }
    }
    if (g == 0) {   // self row, added exactly once
        uint4 v = Hv[((size_t)i << 4) + c16];
        UNPACK8(v);
    }
#pragma unroll
    for (int c = 0; c < 8; ++c) {
        acc[c] += __shfl_xor(acc[c], 16, 64);
        acc[c] += __shfl_xor(acc[c], 32, 64);
    }
    if (g == 0) {
        float dv = dinv[i];
        const float4* bv = (const float4*)bias;
        float4 b0 = bv[c16 * 2], b1 = bv[c16 * 2 + 1];
        float r0 = fmaxf(acc[0] * dv + b0.x, 0.f);
        float r1 = fmaxf(acc[1] * dv + b0.y, 0.f);
        float r2 = fmaxf(acc[2] * dv + b0.z, 0.f);
        float r3 = fmaxf(acc[3] * dv + b0.w, 0.f);
        float r4 = fmaxf(acc[4] * dv + b1.x, 0.f);
        float r5 = fmaxf(acc[5] * dv + b1.y, 0.f);
        float r6 = fmaxf(acc[6] * dv + b1.z, 0.f);
        float r7 = fmaxf(acc[7] * dv + b1.w, 0.f);
        uint4 o;
        o.x = (unsigned)f2bf(r0) | ((unsigned)f2bf(r1) << 16);
        o.y = (unsigned)f2bf(r2) | ((unsigned)f2bf(r3) << 16);
        o.z = (unsigned)f2bf(r4) | ((unsigned)f2bf(r5) << 16);
        o.w = (unsigned)f2bf(r6) | ((unsigned)f2bf(r7) << 16);
        ((uint4*)Out)[((size_t)i << 4) + c16] = o;
    }
}

// ---------- final aggregation (64ch padded, Cout real) + bias + log_softmax ----------
// 4 groups x 16 lanes, dwordx2 (4 ch/lane); after reduce, redistribute so lane L
// owns channel L (4 shfl + 3 selects), then scalar 64-lane softmax (1 exp/lane).
__global__ __launch_bounds__(256) void k_agg3(const unsigned short* __restrict__ H,
                                              const int* __restrict__ row_ptr,
                                              const int* __restrict__ ssrc,
                                              const float* __restrict__ dinv,
                                              const float* __restrict__ b3,
                                              float* __restrict__ Out, int N, int Cout) {
    int lane = threadIdx.x & 63;
    int i = blockIdx.x * 4 + (threadIdx.x >> 6);
    if (i >= N) return;
    int g = lane >> 4;
    int c16 = lane & 15;                    // 8B chunk within the 128B row
    const uint2* Hv = (const uint2*)H;      // row i = 16 uint2
    float acc[4];
#pragma unroll
    for (int c = 0; c < 4; ++c) acc[c] = 0.f;
    int e0 = row_ptr[i], e1 = row_ptr[i + 1];
    for (int base = e0; base < e1; base += 64) {
        int cnt = min(64, e1 - base);
        int sidx = (lane < cnt) ? ssrc[base + lane] : 0;
        int full = cnt & ~3;
#pragma unroll 2
        for (int j = 0; j < full; j += 4) {
            int s = __shfl(sidx, j + g, 64);
            uint2 v = Hv[((size_t)s << 4) + c16];
            UNPACK4(v);
        }
        int jj = full + g;
        if (jj < cnt) {
            int s = __shfl(sidx, jj, 64);
            uint2 v = Hv[((size_t)s << 4) + c16];
            UNPACK4(v);
        }
    }
    if (g == 0) {
        uint2 v = Hv[((size_t)i << 4) + c16];
        UNPACK4(v);
    }
#pragma unroll
    for (int c = 0; c < 4; ++c) {
        acc[c] += __shfl_xor(acc[c], 16, 64);
        acc[c] += __shfl_xor(acc[c], 32, 64);
    }
    // redistribute: lane L <- element (L&3) of lane (L>>2)'s acc
    float t0 = __shfl(acc[0], lane >> 2, 64);
    float t1 = __shfl(acc[1], lane >> 2, 64);
    float t2 = __shfl(acc[2], lane >> 2, 64);
    float t3 = __shfl(acc[3], lane >> 2, 64);
    float a01 = (lane & 1) ? t1 : t0;
    float a23 = (lane & 1) ? t3 : t2;
    float av  = (lane & 2) ? a23 : a01;
    float dv = dinv[i];
    float z = (lane < Cout) ? av * dv + b3[lane] : -1e30f;
    float m = z;
    for (int off = 32; off; off >>= 1) m = fmaxf(m, __shfl_xor(m, off, 64));
    float pexp = (lane < Cout) ? expf(z - m) : 0.f;
    float ssum = pexp;
    for (int off = 32; off; off >>= 1) ssum += __shfl_xor(ssum, off, 64);
    if (lane < Cout) Out[(size_t)i * Cout + lane] = z - m - logf(ssum);
}

extern "C" void kernel_launch(void* const* d_in, const int* in_sizes, int n_in,
                              void* d_out, int out_size, void* d_ws, size_t ws_size,
                              hipStream_t stream) {
    const float* x  = (const float*)d_in[0];
    const int*   ei = (const int*)d_in[1];
    const float* W1 = (const float*)d_in[2];
    const float* b1 = (const float*)d_in[3];
    const float* W2 = (const float*)d_in[4];
    const float* b2 = (const float*)d_in[5];
    const float* W3 = (const float*)d_in[6];
    const float* b3 = (const float*)d_in[7];

    const int N = in_sizes[0] / 128;
    const int E = in_sizes[1] / 2;
    const int Cout = in_sizes[7];       // 47
    const int Npad = (N + 63) & ~63;
    const int* srcp = ei;
    const int* dstp = ei + E;

    const int NB  = (N + 511) >> 9;             // coarse buckets (196), must be <= 256
    const int nPB = (E + CHB - 1) / CHB;        // partition blocks (196)
    const int M   = NB * nPB;                   // bhist size (38416)

    // ---- workspace partition (256B aligned) ----
    char* p = (char*)d_ws;
    auto alloc = [&](size_t bytes) -> void* {
        void* r = (void*)p;
        p += (bytes + 255) & ~(size_t)255;
        return r;
    };
    float* dinv     = (float*)alloc((size_t)Npad * 4);
    int*   row_ptr  = (int*)alloc((size_t)(N + 1) * 4);
    int*   bhist    = (int*)alloc((size_t)M * 4);
    int*   bscan    = (int*)alloc((size_t)(M + 1) * 4);
    int*   part     = (int*)alloc(1024 * 4);
    unsigned* pedge = (unsigned*)alloc((size_t)E * 4);
    int*   ssrc     = (int*)alloc((size_t)E * 4);
    unsigned short* xb  = (unsigned short*)alloc((size_t)Npad * 128 * 2);
    unsigned short* hb  = (unsigned short*)alloc((size_t)Npad * 128 * 2);
    unsigned short* ab  = (unsigned short*)alloc((size_t)Npad * 128 * 2);
    unsigned short* wf1 = (unsigned short*)alloc(128 * 128 * 2);
    unsigned short* wf2 = (unsigned short*)alloc(128 * 128 * 2);
    unsigned short* wf3 = (unsigned short*)alloc(128 * 64 * 2);

    // ---- CSR build: hist -> scan -> partition -> per-bucket counting sort ----
    const int nb2 = (M + 1023) / 1024;          // 38 blocks (<= 256)
    k_hist<<<nPB, 256, 0, stream>>>(dstp, E, nPB, bhist, NB);
    k_scan_part<<<nb2, 256, 0, stream>>>(bhist, part, M);
    k_scan_mid<<<1, 256, 0, stream>>>(part, nb2);
    k_scan_final<<<nb2, 256, 0, stream>>>(bhist, part, bscan, M);
    k_partition<<<nPB, 256, 0, stream>>>(srcp, dstp, E, nPB, bscan, pedge, NB);
    k_bucket<<<NB, 256, 0, stream>>>(pedge, bscan, nPB, N, Npad, row_ptr, dinv, ssrc);

    // conversions
    k_cvt_x<<<(N * 128 / 4 + 255) / 256, 256, 0, stream>>>((const float4*)x, (ushort4*)xb,
                                                           N * 128 / 4);
    k_wfrag<<<(16384 + 255) / 256, 256, 0, stream>>>(W1, wf1, 128, 128);
    k_wfrag<<<(16384 + 255) / 256, 256, 0, stream>>>(W2, wf2, 128, 128);
    k_wfrag<<<(8192 + 255) / 256, 256, 0, stream>>>(W3, wf3, 64, Cout);

    const int gemmGrid = Npad / 64;
    const int aggGrid = (N + 3) / 4;

    // layer 1
    k_gemm<8><<<gemmGrid, 256, 0, stream>>>(xb, wf1, dinv, hb);
    k_agg<<<aggGrid, 256, 0, stream>>>(hb, row_ptr, ssrc, dinv, b1, ab, N);
    // layer 2
    k_gemm<8><<<gemmGrid, 256, 0, stream>>>(ab, wf2, dinv, hb);
    k_agg<<<aggGrid, 256, 0, stream>>>(hb, row_ptr, ssrc, dinv, b2, ab, N);
    // layer 3 (output padded to 64 cols) + log_softmax
    k_gemm<4><<<gemmGrid, 256, 0, stream>>>(ab, wf3, dinv, hb);
    k_agg3<<<aggGrid, 256, 0, stream>>>(hb, row_ptr, ssrc, dinv, b3,
                                        (float*)d_out, N, Cout);
}

// Round 7
// 303.718 us; speedup vs baseline: 1.6184x; 1.0025x over previous
//
#include <hip/hip_runtime.h>
#include <stdint.h>

typedef __bf16 bf16x8 __attribute__((ext_vector_type(8)));
typedef float f32x4 __attribute__((ext_vector_type(4)));

#define CHB 8192  // edges per partition block

__device__ __forceinline__ float bf2f(unsigned short s) {
    union { unsigned u; float f; } x; x.u = ((unsigned)s) << 16; return x.f;
}
__device__ __forceinline__ float bitf(unsigned u) {
    union { unsigned u; float f; } x; x.u = u; return x.f;
}
__device__ __forceinline__ unsigned short f2bf(float f) {
    union { float f; unsigned u; } x; x.f = f;
    unsigned r = x.u + 0x7fffu + ((x.u >> 16) & 1u);
    return (unsigned short)(r >> 16);
}

// acc += pk.bf16[0]*sel.bf16[0] + pk.bf16[1]*sel.bf16[1]  (one VOP3P op)
__device__ __forceinline__ void dot2acc(float& a, unsigned pk, unsigned sel) {
    asm("v_dot2_f32_bf16 %0, %1, %2, %0" : "+v"(a) : "v"(pk), "v"(sel));
}

// ---------- pass A: per-(bucket,block) histogram. bucket = dst>>9 ----------
__global__ __launch_bounds__(256) void k_hist(const int* __restrict__ dst, int E, int nPB,
                                              int* __restrict__ bhist, int NB) {
    __shared__ int h[256];
    int t = threadIdx.x;
    h[t] = 0;
    __syncthreads();
    int blk = blockIdx.x;
    int hi = min((blk + 1) * CHB, E);
    for (int e = blk * CHB + t; e < hi; e += 256) atomicAdd(&h[dst[e] >> 9], 1);
    __syncthreads();
    if (t < NB) bhist[t * nPB + blk] = h[t];
}

// ---------- hierarchical scan (generic): in[M] -> out[M+1] exclusive ----------
__global__ __launch_bounds__(256) void k_scan_part(const int* __restrict__ deg,
                                                   int* __restrict__ part, int N) {
    __shared__ int wsum[4];
    int t = threadIdx.x;
    int lane = t & 63, wv = t >> 6;
    int base = blockIdx.x * 1024 + t * 4;
    int s = 0;
#pragma unroll
    for (int j = 0; j < 4; ++j) {
        int i = base + j;
        if (i < N) s += deg[i];
    }
    for (int off = 1; off < 64; off <<= 1) s += __shfl_xor(s, off, 64);
    if (lane == 0) wsum[wv] = s;
    __syncthreads();
    if (t == 0) part[blockIdx.x] = wsum[0] + wsum[1] + wsum[2] + wsum[3];
}

__global__ void k_scan_mid(int* __restrict__ part, int nb) {
    __shared__ int buf[256];
    int t = threadIdx.x;
    buf[t] = (t < nb) ? part[t] : 0;
    __syncthreads();
    for (int off = 1; off < 256; off <<= 1) {
        int v = buf[t];
        int u = (t >= off) ? buf[t - off] : 0;
        __syncthreads();
        buf[t] = v + u;
        __syncthreads();
    }
    if (t < nb) part[t] = (t == 0) ? 0 : buf[t - 1];
}

__global__ __launch_bounds__(256) void k_scan_final(const int* __restrict__ deg,
                                                    const int* __restrict__ part,
                                                    int* __restrict__ out, int N) {
    __shared__ int wsum[4];
    int t = threadIdx.x;
    int lane = t & 63, wv = t >> 6;
    int base = blockIdx.x * 1024 + t * 4;
    int v[4];
    int s = 0;
#pragma unroll
    for (int j = 0; j < 4; ++j) {
        int i = base + j;
        v[j] = (i < N) ? deg[i] : 0;
        s += v[j];
    }
    int inc = s;
    for (int off = 1; off < 64; off <<= 1) {
        int u = __shfl_up(inc, off, 64);
        if (lane >= off) inc += u;
    }
    if (lane == 63) wsum[wv] = inc;
    __syncthreads();
    int excl = part[blockIdx.x] + inc - s;
    for (int w = 0; w < wv; ++w) excl += wsum[w];
#pragma unroll
    for (int j = 0; j < 4; ++j) {
        int i = base + j;
        if (i < N) {
            out[i] = excl;
            excl += v[j];
            if (i == N - 1) out[N] = excl;
        }
    }
}

// ---------- pass B: partition edges into bucket-contiguous regions ----------
__global__ __launch_bounds__(256) void k_partition(const int* __restrict__ src,
                                                   const int* __restrict__ dst, int E,
                                                   int nPB, const int* __restrict__ bscan,
                                                   unsigned* __restrict__ part_edges, int NB) {
    __shared__ int cur[256];
    int t = threadIdx.x;
    int blk = blockIdx.x;
    if (t < NB) cur[t] = bscan[t * nPB + blk];
    __syncthreads();
    int hi = min((blk + 1) * CHB, E);
    for (int e = blk * CHB + t; e < hi; e += 256) {
        int d = dst[e];
        int s = src[e];
        int pos = atomicAdd(&cur[d >> 9], 1);
        part_edges[pos] = ((unsigned)(d & 511) << 17) | (unsigned)s;
    }
}

// ---------- pass C: per-bucket counting sort -> row_ptr, dinv, ssrc ----------
__global__ __launch_bounds__(256) void k_bucket(const unsigned* __restrict__ part_edges,
                                                const int* __restrict__ bscan, int nPB,
                                                int N, int Npad, int* __restrict__ row_ptr,
                                                float* __restrict__ dinv,
                                                int* __restrict__ ssrc) {
    __shared__ int cnt[512];
    __shared__ int excl[512];
    __shared__ int wsum[4];
    int t = threadIdx.x;
    int b = blockIdx.x;
    int pb = bscan[b * nPB];
    int pe = bscan[(b + 1) * nPB];   // bscan[M] == E for the last bucket
    cnt[t] = 0; cnt[t + 256] = 0;
    __syncthreads();
    for (int e = pb + t; e < pe; e += 256)
        atomicAdd(&cnt[(part_edges[e] >> 17) & 511], 1);
    __syncthreads();
    int a0 = cnt[2 * t], a1 = cnt[2 * t + 1];
    int s = a0 + a1;
    int lane = t & 63, wv = t >> 6;
    int inc = s;
    for (int off = 1; off < 64; off <<= 1) {
        int u = __shfl_up(inc, off, 64);
        if (lane >= off) inc += u;
    }
    if (lane == 63) wsum[wv] = inc;
    __syncthreads();
    int pre = inc - s;
    for (int w = 0; w < wv; ++w) pre += wsum[w];
    excl[2 * t] = pre;
    excl[2 * t + 1] = pre + a0;
    int base = b << 9;
#pragma unroll
    for (int j = 0; j < 2; ++j) {
        int i = 2 * t + j;
        int g = base + i;
        int c = (j == 0) ? a0 : a1;
        int ex = (j == 0) ? pre : pre + a0;
        if (g < N) {
            row_ptr[g] = pb + ex;
            if (g == N - 1) row_ptr[N] = pb + ex + c;
        }
        if (g < Npad) dinv[g] = rsqrtf((float)c + 1.0f);
    }
    __syncthreads();
    for (int e = pb + t; e < pe; e += 256) {
        unsigned pk = part_edges[e];
        int doff = (pk >> 17) & 511;
        int pos = pb + atomicAdd(&excl[doff], 1);
        ssrc[pos] = (int)(pk & 0x1FFFFu);
    }
}

// ---------- conversions ----------
__global__ void k_cvt_x(const float4* __restrict__ x, ushort4* __restrict__ out, int n4) {
    int i = blockIdx.x * blockDim.x + threadIdx.x;
    if (i < n4) {
        float4 v = x[i];
        ushort4 o;
        o.x = f2bf(v.x); o.y = f2bf(v.y); o.z = f2bf(v.z); o.w = f2bf(v.w);
        out[i] = o;
    }
}

// W [K=128][realCols] f32 row-major -> fragment layout bf16:
// Wf[((kk*NT + n)*64 + lane)*8 + j] = W[kk*32 + (lane>>4)*8 + j][n*16 + (lane&15)]
__global__ void k_wfrag(const float* __restrict__ W, unsigned short* __restrict__ Wf,
                        int Ncol, int realCols) {
    int NT = Ncol >> 4;
    int total = 4 * NT * 64 * 8;
    int idx = blockIdx.x * blockDim.x + threadIdx.x;
    if (idx >= total) return;
    int j = idx & 7;
    int l = (idx >> 3) & 63;
    int t = idx >> 9;          // kk*NT + n
    int n = t % NT;
    int kk = t / NT;
    int k = kk * 32 + ((l >> 4) << 3) + j;
    int c = (n << 4) + (l & 15);
    float v = (c < realCols) ? W[k * realCols + c] : 0.0f;
    Wf[idx] = f2bf(v);
}

// ---------- GEMM: H'[Npad][NT*16] = dinv[row] * (A[Npad][128] @ W) ----------
template<int NT>
__global__ __launch_bounds__(256) void k_gemm(const unsigned short* __restrict__ A,
                                              const unsigned short* __restrict__ Wf,
                                              const float* __restrict__ dinv,
                                              unsigned short* __restrict__ Hout) {
    int lane = threadIdx.x & 63;
    int wv = threadIdx.x >> 6;
    int rb = blockIdx.x * 4 + wv;
    size_t row0 = (size_t)rb * 16;
    const unsigned short* arow = A + (row0 + (lane & 15)) * 128 + ((lane >> 4) << 3);
    f32x4 acc[NT];
#pragma unroll
    for (int n = 0; n < NT; ++n) acc[n] = (f32x4){0.f, 0.f, 0.f, 0.f};
#pragma unroll
    for (int kk = 0; kk < 4; ++kk) {
        bf16x8 a = *(const bf16x8*)(arow + kk * 32);
#pragma unroll
        for (int n = 0; n < NT; ++n) {
            bf16x8 b = *(const bf16x8*)(Wf + (((kk * NT + n) * 64 + lane) << 3));
            acc[n] = __builtin_amdgcn_mfma_f32_16x16x32_bf16(a, b, acc[n], 0, 0, 0);
        }
    }
    const int NCOL = NT * 16;
    size_t crow = row0 + ((lane >> 4) << 2);
    int ccol = lane & 15;
    float dv[4];
#pragma unroll
    for (int q = 0; q < 4; ++q) dv[q] = dinv[crow + q];
#pragma unroll
    for (int n = 0; n < NT; ++n) {
#pragma unroll
        for (int q = 0; q < 4; ++q) {
            Hout[(crow + q) * NCOL + n * 16 + ccol] = f2bf(acc[n][q] * dv[q]);
        }
    }
}

// selector constants: bf16 pair (1.0, 0.0) and (0.0, 1.0)
#define SEL_LO 0x00003F80u
#define SEL_HI 0x3F800000u

#define DOT8(v)                                      \
    dot2acc(acc[0], (v).x, sel_lo); dot2acc(acc[1], (v).x, sel_hi); \
    dot2acc(acc[2], (v).y, sel_lo); dot2acc(acc[3], (v).y, sel_hi); \
    dot2acc(acc[4], (v).z, sel_lo); dot2acc(acc[5], (v).z, sel_hi); \
    dot2acc(acc[6], (v).w, sel_lo); dot2acc(acc[7], (v).w, sel_hi);

#define DOT4(v)                                      \
    dot2acc(acc[0], (v).x, sel_lo); dot2acc(acc[1], (v).x, sel_hi); \
    dot2acc(acc[2], (v).y, sel_lo); dot2acc(acc[3], (v).y, sel_hi);

// ---------- aggregation (128 ch): one wave per dst node ----------
// 4 groups x 16 lanes; group g gathers edge (j+g) with dwordx4 (8 ch/lane);
// dot2-based accumulate (1 VALU op per 2 channels); cross-group reduce at end.
__global__ __launch_bounds__(256) void k_agg(const unsigned short* __restrict__ H,
                                             const int* __restrict__ row_ptr,
                                             const int* __restrict__ ssrc,
                                             const float* __restrict__ dinv,
                                             const float* __restrict__ bias,
                                             unsigned short* __restrict__ Out, int N) {
    int lane = threadIdx.x & 63;
    int i = blockIdx.x * 4 + (threadIdx.x >> 6);
    if (i >= N) return;
    unsigned sel_lo = SEL_LO, sel_hi = SEL_HI;
    int g = lane >> 4;
    int c16 = lane & 15;                    // 16B chunk within the 256B row
    const uint4* Hv = (const uint4*)H;      // row i = 16 uint4
    float acc[8];
#pragma unroll
    for (int c = 0; c < 8; ++c) acc[c] = 0.f;
    int e0 = row_ptr[i], e1 = row_ptr[i + 1];
    for (int base = e0; base < e1; base += 64) {
        int cnt = min(64, e1 - base);
        int sidx = (lane < cnt) ? ssrc[base + lane] : 0;
        int full = cnt & ~3;
#pragma unroll 4
        for (int j = 0; j < full; j += 4) {
            int s = __shfl(sidx, j + g, 64);
            uint4 v = Hv[((size_t)s << 4) + c16];
            DOT8(v);
        }
        int jj = full + g;
        if (jj < cnt) {
            int s = __shfl(sidx, jj, 64);
            uint4 v = Hv[((size_t)s << 4) + c16];
            DOT8(v);
        }
    }
    if (g == 0) {   // self row, added exactly once
        uint4 v = Hv[((size_t)i << 4) + c16];
        DOT8(v);
    }
#pragma unroll
    for (int c = 0; c < 8; ++c) {
        acc[c] += __shfl_xor(acc[c], 16, 64);
        acc[c] += __shfl_xor(acc[c], 32, 64);
    }
    if (g == 0) {
        float dv = dinv[i];
        const float4* bv = (const float4*)bias;
        float4 b0 = bv[c16 * 2], b1 = bv[c16 * 2 + 1];
        float r0 = fmaxf(acc[0] * dv + b0.x, 0.f);
        float r1 = fmaxf(acc[1] * dv + b0.y, 0.f);
        float r2 = fmaxf(acc[2] * dv + b0.z, 0.f);
        float r3 = fmaxf(acc[3] * dv + b0.w, 0.f);
        float r4 = fmaxf(acc[4] * dv + b1.x, 0.f);
        float r5 = fmaxf(acc[5] * dv + b1.y, 0.f);
        float r6 = fmaxf(acc[6] * dv + b1.z, 0.f);
        float r7 = fmaxf(acc[7] * dv + b1.w, 0.f);
        uint4 o;
        o.x = (unsigned)f2bf(r0) | ((unsigned)f2bf(r1) << 16);
        o.y = (unsigned)f2bf(r2) | ((unsigned)f2bf(r3) << 16);
        o.z = (unsigned)f2bf(r4) | ((unsigned)f2bf(r5) << 16);
        o.w = (unsigned)f2bf(r6) | ((unsigned)f2bf(r7) << 16);
        ((uint4*)Out)[((size_t)i << 4) + c16] = o;
    }
}

// ---------- final aggregation (64ch padded, Cout real) + bias + log_softmax ----------
// 4 groups x 16 lanes, dwordx2 (4 ch/lane); after reduce, redistribute so lane L
// owns channel L (4 shfl + 3 selects), then scalar 64-lane softmax (1 exp/lane).
__global__ __launch_bounds__(256) void k_agg3(const unsigned short* __restrict__ H,
                                              const int* __restrict__ row_ptr,
                                              const int* __restrict__ ssrc,
                                              const float* __restrict__ dinv,
                                              const float* __restrict__ b3,
                                              float* __restrict__ Out, int N, int Cout) {
    int lane = threadIdx.x & 63;
    int i = blockIdx.x * 4 + (threadIdx.x >> 6);
    if (i >= N) return;
    unsigned sel_lo = SEL_LO, sel_hi = SEL_HI;
    int g = lane >> 4;
    int c16 = lane & 15;                    // 8B chunk within the 128B row
    const uint2* Hv = (const uint2*)H;      // row i = 16 uint2
    float acc[4];
#pragma unroll
    for (int c = 0; c < 4; ++c) acc[c] = 0.f;
    int e0 = row_ptr[i], e1 = row_ptr[i + 1];
    for (int base = e0; base < e1; base += 64) {
        int cnt = min(64, e1 - base);
        int sidx = (lane < cnt) ? ssrc[base + lane] : 0;
        int full = cnt & ~3;
#pragma unroll 4
        for (int j = 0; j < full; j += 4) {
            int s = __shfl(sidx, j + g, 64);
            uint2 v = Hv[((size_t)s << 4) + c16];
            DOT4(v);
        }
        int jj = full + g;
        if (jj < cnt) {
            int s = __shfl(sidx, jj, 64);
            uint2 v = Hv[((size_t)s << 4) + c16];
            DOT4(v);
        }
    }
    if (g == 0) {
        uint2 v = Hv[((size_t)i << 4) + c16];
        DOT4(v);
    }
#pragma unroll
    for (int c = 0; c < 4; ++c) {
        acc[c] += __shfl_xor(acc[c], 16, 64);
        acc[c] += __shfl_xor(acc[c], 32, 64);
    }
    // redistribute: lane L <- element (L&3) of lane (L>>2)'s acc
    float t0 = __shfl(acc[0], lane >> 2, 64);
    float t1 = __shfl(acc[1], lane >> 2, 64);
    float t2 = __shfl(acc[2], lane >> 2, 64);
    float t3 = __shfl(acc[3], lane >> 2, 64);
    float a01 = (lane & 1) ? t1 : t0;
    float a23 = (lane & 1) ? t3 : t2;
    float av  = (lane & 2) ? a23 : a01;
    float dv = dinv[i];
    float z = (lane < Cout) ? av * dv + b3[lane] : -1e30f;
    float m = z;
    for (int off = 32; off; off >>= 1) m = fmaxf(m, __shfl_xor(m, off, 64));
    float pexp = (lane < Cout) ? expf(z - m) : 0.f;
    float ssum = pexp;
    for (int off = 32; off; off >>= 1) ssum += __shfl_xor(ssum, off, 64);
    if (lane < Cout) Out[(size_t)i * Cout + lane] = z - m - logf(ssum);
}

extern "C" void kernel_launch(void* const* d_in, const int* in_sizes, int n_in,
                              void* d_out, int out_size, void* d_ws, size_t ws_size,
                              hipStream_t stream) {
    const float* x  = (const float*)d_in[0];
    const int*   ei = (const int*)d_in[1];
    const float* W1 = (const float*)d_in[2];
    const float* b1 = (const float*)d_in[3];
    const float* W2 = (const float*)d_in[4];
    const float* b2 = (const float*)d_in[5];
    const float* W3 = (const float*)d_in[6];
    const float* b3 = (const float*)d_in[7];

    const int N = in_sizes[0] / 128;
    const int E = in_sizes[1] / 2;
    const int Cout = in_sizes[7];       // 47
    const int Npad = (N + 63) & ~63;
    const int* srcp = ei;
    const int* dstp = ei + E;

    const int NB  = (N + 511) >> 9;             // coarse buckets (196), must be <= 256
    const int nPB = (E + CHB - 1) / CHB;        // partition blocks (196)
    const int M   = NB * nPB;                   // bhist size (38416)

    // ---- workspace partition (256B aligned) ----
    char* p = (char*)d_ws;
    auto alloc = [&](size_t bytes) -> void* {
        void* r = (void*)p;
        p += (bytes + 255) & ~(size_t)255;
        return r;
    };
    float* dinv     = (float*)alloc((size_t)Npad * 4);
    int*   row_ptr  = (int*)alloc((size_t)(N + 1) * 4);
    int*   bhist    = (int*)alloc((size_t)M * 4);
    int*   bscan    = (int*)alloc((size_t)(M + 1) * 4);
    int*   part     = (int*)alloc(1024 * 4);
    unsigned* pedge = (unsigned*)alloc((size_t)E * 4);
    int*   ssrc     = (int*)alloc((size_t)E * 4);
    unsigned short* xb  = (unsigned short*)alloc((size_t)Npad * 128 * 2);
    unsigned short* hb  = (unsigned short*)alloc((size_t)Npad * 128 * 2);
    unsigned short* ab  = (unsigned short*)alloc((size_t)Npad * 128 * 2);
    unsigned short* wf1 = (unsigned short*)alloc(128 * 128 * 2);
    unsigned short* wf2 = (unsigned short*)alloc(128 * 128 * 2);
    unsigned short* wf3 = (unsigned short*)alloc(128 * 64 * 2);

    // ---- CSR build: hist -> scan -> partition -> per-bucket counting sort ----
    const int nb2 = (M + 1023) / 1024;          // 38 blocks (<= 256)
    k_hist<<<nPB, 256, 0, stream>>>(dstp, E, nPB, bhist, NB);
    k_scan_part<<<nb2, 256, 0, stream>>>(bhist, part, M);
    k_scan_mid<<<1, 256, 0, stream>>>(part, nb2);
    k_scan_final<<<nb2, 256, 0, stream>>>(bhist, part, bscan, M);
    k_partition<<<nPB, 256, 0, stream>>>(srcp, dstp, E, nPB, bscan, pedge, NB);
    k_bucket<<<NB, 256, 0, stream>>>(pedge, bscan, nPB, N, Npad, row_ptr, dinv, ssrc);

    // conversions
    k_cvt_x<<<(N * 128 / 4 + 255) / 256, 256, 0, stream>>>((const float4*)x, (ushort4*)xb,
                                                           N * 128 / 4);
    k_wfrag<<<(16384 + 255) / 256, 256, 0, stream>>>(W1, wf1, 128, 128);
    k_wfrag<<<(16384 + 255) / 256, 256, 0, stream>>>(W2, wf2, 128, 128);
    k_wfrag<<<(8192 + 255) / 256, 256, 0, stream>>>(W3, wf3, 64, Cout);

    const int gemmGrid = Npad / 64;
    const int aggGrid = (N + 3) / 4;

    // layer 1
    k_gemm<8><<<gemmGrid, 256, 0, stream>>>(xb, wf1, dinv, hb);
    k_agg<<<aggGrid, 256, 0, stream>>>(hb, row_ptr, ssrc, dinv, b1, ab, N);
    // layer 2
    k_gemm<8><<<gemmGrid, 256, 0, stream>>>(ab, wf2, dinv, hb);
    k_agg<<<aggGrid, 256, 0, stream>>>(hb, row_ptr, ssrc, dinv, b2, ab, N);
    // layer 3 (output padded to 64 cols) + log_softmax
    k_gemm<4><<<gemmGrid, 256, 0, stream>>>(ab, wf3, dinv, hb);
    k_agg3<<<aggGrid, 256, 0, stream>>>(hb, row_ptr, ssrc, dinv, b3,
                                        (float*)d_out, N, Cout);
}